// Round 6
// baseline (17.990 us; speedup 1.0000x reference)
//
#include <hip/hip_runtime.h>

#define NFEAT 2000
#define NMID  1998
#define BATCH 4096
#define PI_2  1.57079632679489662f

// Column-decomposition MPS chain, left-to-right only.
//   lane l of a 16-lane group owns component l of the bond vector.
//   v'[l] = sum_d v[d] * (c*M[d][0][l] + s*M[d][1][l])
// For fixed (d,p) the 16 lanes read 64 contiguous bytes of cm -> coalesced.
// Full-v redistribution goes through a tiny LDS buffer; each group lives
// inside one wave, so DS ops are wave-ordered (no barriers).
//
// EARLY EXIT: cores are 0.01-scale, so ||v|| contracts ~25x per step and v
// hits exact fp32 zero after ~30 steps. Zero is absorbing (0-vector in,
// 0-vector out, exactly), so once the wave's 4 samples are all-zero the
// remaining chain is provably a no-op. Vote every step (exact for any input:
// non-decaying inputs just run the full chain).
//
// FTZ: flush f32 denormals (MODE.FP_DENORM f32 field = 0) so the decay
// reaches exact zero at the normal-number floor (~1.2e-38) instead of
// crawling ~5 more steps through denormals to 1.4e-45. Zero remains
// absorbing; output for decaying inputs is identical (exact 0).

#define REFILL(A, mm) do {                                                  \
    const float* _p = cm + (size_t)(mm) * 512 + l;                          \
    _Pragma("unroll")                                                       \
    for (int _d = 0; _d < 16; ++_d) {                                       \
        A[_d]      = _p[_d * 32];                                           \
        A[16 + _d] = _p[_d * 32 + 16];                                      \
    } } while (0)

// 4 independent accumulator chains + 2-level tree: dep chain ~24cyc vs 64.
#define DOT16(R, A, OFF) do {                                               \
    float _r0 = W[0].x * A[OFF + 0];                                        \
    _r0 = fmaf(W[0].y, A[OFF + 1], _r0);                                    \
    _r0 = fmaf(W[0].z, A[OFF + 2], _r0);                                    \
    _r0 = fmaf(W[0].w, A[OFF + 3], _r0);                                    \
    float _r1 = W[1].x * A[OFF + 4];                                        \
    _r1 = fmaf(W[1].y, A[OFF + 5], _r1);                                    \
    _r1 = fmaf(W[1].z, A[OFF + 6], _r1);                                    \
    _r1 = fmaf(W[1].w, A[OFF + 7], _r1);                                    \
    float _r2 = W[2].x * A[OFF + 8];                                        \
    _r2 = fmaf(W[2].y, A[OFF + 9], _r2);                                    \
    _r2 = fmaf(W[2].z, A[OFF + 10], _r2);                                   \
    _r2 = fmaf(W[2].w, A[OFF + 11], _r2);                                   \
    float _r3 = W[3].x * A[OFF + 12];                                       \
    _r3 = fmaf(W[3].y, A[OFF + 13], _r3);                                   \
    _r3 = fmaf(W[3].z, A[OFF + 14], _r3);                                   \
    _r3 = fmaf(W[3].w, A[OFF + 15], _r3);                                   \
    R = (_r0 + _r1) + (_r2 + _r3);                                          \
    } while (0)

#define STEP(A, XV) do {                                                    \
    const float _th = (XV) * PI_2;                                          \
    const float _c = __cosf(_th), _s = __sinf(_th);                         \
    float _dA, _dB;                                                         \
    DOT16(_dA, A, 0);                                                       \
    DOT16(_dB, A, 16);                                                      \
    v = fmaf(_c, _dA, _s * _dB);                                            \
    } while (0)

#define EXCH() do {                                                         \
    vx[g][l] = v;                                                           \
    W[0] = *(const float4*)&vx[g][0];                                       \
    W[1] = *(const float4*)&vx[g][4];                                       \
    W[2] = *(const float4*)&vx[g][8];                                       \
    W[3] = *(const float4*)&vx[g][12];                                      \
    } while (0)

__global__ __launch_bounds__(256, 1)
void mps_col_kernel(const float* __restrict__ x,  const float* __restrict__ cf,
                    const float* __restrict__ cm, const float* __restrict__ cl,
                    float* __restrict__ out)
{
    // flush f32 denormals to zero (MODE.FP_DENORM bits [5:4] = 0)
    asm volatile("s_setreg_imm32_b32 hwreg(HW_REG_MODE, 4, 2), 0");

    __shared__ float vx[16][20];   // padded group exchange buffer

    const int tid = threadIdx.x;
    const int g   = tid >> 4;      // sample slot 0..15
    const int l   = tid & 15;      // bond lane 0..15
    const int b   = blockIdx.x * 16 + g;
    const size_t xrow = (size_t)b * NFEAT;

    // ---- v0 from core_first, feature 0 ----
    float v;
    {
        const float th = x[xrow] * PI_2;
        v = fmaf(__sinf(th), cf[16 + l], __cosf(th) * cf[l]);
    }

    float4 W[4];
    EXCH();                        // distribute v0 to the group

    // ---- pipeline prologue: columns for steps 0 and 1, features 1 and 2 ----
    float a0[32], a1[32];
    REFILL(a0, 0);
    REFILL(a1, 1);
    float xa = x[xrow + 1];
    float xb = x[xrow + 2];

    bool dead = false;
    for (int m = 0; m < NMID - 2; m += 2) {
        STEP(a0, xa);              // step m
        if (__all(v == 0.0f)) { dead = true; break; }
        EXCH();
        REFILL(a0, m + 2);         // refill one full step ahead of use
        xa = x[xrow + m + 3];
        STEP(a1, xb);              // step m+1
        if (__all(v == 0.0f)) { dead = true; break; }
        EXCH();
        REFILL(a1, m + 3);
        xb = x[xrow + m + 4];
    }
    if (!dead) {                   // tail: steps 1996, 1997 (already in a0/a1)
        STEP(a0, xa);
        EXCH();
        STEP(a1, xb);
    }

    // ---- epilogue: out[b] = sum_l v[l] * (c*cl[l][0] + s*cl[l][1]) ----
    {
        const float th = x[xrow + NFEAT - 1] * PI_2;
        float p = v * fmaf(__sinf(th), cl[2 * l + 1], __cosf(th) * cl[2 * l]);
        p += __shfl_xor(p, 1);
        p += __shfl_xor(p, 2);
        p += __shfl_xor(p, 4);
        p += __shfl_xor(p, 8);
        if (l == 0) out[b] = p;
    }
}

extern "C" void kernel_launch(void* const* d_in, const int* in_sizes, int n_in,
                              void* d_out, int out_size, void* d_ws, size_t ws_size,
                              hipStream_t stream) {
    const float* x  = (const float*)d_in[0];
    const float* cf = (const float*)d_in[1];
    const float* cm = (const float*)d_in[2];
    const float* cl = (const float*)d_in[3];
    float* out = (float*)d_out;
    hipLaunchKernelGGL(mps_col_kernel, dim3(BATCH / 16), dim3(256), 0, stream,
                       x, cf, cm, cl, out);
}